// Round 10
// baseline (502.466 us; speedup 1.0000x reference)
//
#include <hip/hip_runtime.h>
#include <hip/hip_cooperative_groups.h>
#include <math.h>

namespace cg = cooperative_groups;

#define NEG_SLOPE 0.2f
#define CAP 128     // max degree on the agg fast path (Poisson(17): P(deg>128) ~ 0; slow path covers)
#define BSH 9       // node-bucket shift: 512 nodes/bucket
#define BSZ 512
#define CHUNK 4096  // edges per scatter chunk
#define PADS 16     // counter padding (ints) -> one counter per 64B line
#define CAPQ 16384  // fixed bucket capacity (mean ~8.2K, sigma ~90 -> never overflows)

typedef __attribute__((ext_vector_type(8))) short short8;   // 8 bf16 (4 VGPRs)
typedef __attribute__((ext_vector_type(4))) float f32x4;    // MFMA C/D

__device__ __forceinline__ float hred_sum(float v) {   // 32-wide (half-wave) reduce
#pragma unroll
    for (int o = 16; o >= 1; o >>= 1) v += __shfl_xor(v, o, 64);
    return v;
}
// fp32 -> bf16 (RNE), and bf16(lo/hi of uint) -> fp32
__device__ __forceinline__ unsigned int f2bf(float f) {
    unsigned int u = __float_as_uint(f);
    return (u + 0x7fffu + ((u >> 16) & 1u)) >> 16;
}
__device__ __forceinline__ float bflo(unsigned int u) { return __uint_as_float(u << 16); }
__device__ __forceinline__ float bfhi(unsigned int u) { return __uint_as_float(u & 0xffff0000u); }

// ---------------- scatter bodies ---------------------------------------------

// 512-thread variant (mega-kernel): 8 edges/thread per CHUNK of 4096.
__device__ __forceinline__ void scatter512_body(char* smemraw, int bid,
        const int* __restrict__ src, const int* __restrict__ dst,
        int* __restrict__ bcursor, int* __restrict__ ebuf, int E) {
    int* lh = (int*)smemraw;
    int* lb = lh + 256;
    const int tid = threadIdx.x;
    int base = bid * CHUNK;
    int sv[8], dv[8];
    bool ok[8];
#pragma unroll
    for (int u = 0; u < 8; ++u) {
        int i = base + u * 512 + tid;
        ok[u] = i < E;
        int ii = ok[u] ? i : E - 1;
        dv[u] = dst[ii];
        sv[u] = src[ii];
    }
    if (tid < 256) lh[tid] = 0;
    __syncthreads();
#pragma unroll
    for (int u = 0; u < 8; ++u)
        if (ok[u]) atomicAdd(&lh[dv[u] >> BSH], 1);
    __syncthreads();
    if (tid < 256) {
        int c = lh[tid];
        lb[tid] = c ? atomicAdd(&bcursor[tid * PADS], c) : 0;
        lh[tid] = 0;
    }
    __syncthreads();
#pragma unroll
    for (int u = 0; u < 8; ++u) {
        if (ok[u]) {
            int d = dv[u], b = d >> BSH;
            int pp = atomicAdd(&lh[b], 1);
            int pos = lb[b] + pp;
            if (pos < CAPQ)
                ebuf[b * CAPQ + pos] = (sv[u] << BSH) | (d & (BSZ - 1));
        }
    }
    __syncthreads();   // lh/lb reuse safety across chunks
}

// 256-thread standalone (fallback path; verified).
__global__ __launch_bounds__(256) void k_scatter(
        const int* __restrict__ src, const int* __restrict__ dst,
        int* __restrict__ bcursor, int* __restrict__ ebuf, int E) {
    __shared__ int lh[256], lb[256];
    const int tid = threadIdx.x;
    int base = blockIdx.x * CHUNK;
    int sv[16], dv[16];
    bool ok[16];
#pragma unroll
    for (int u = 0; u < 16; ++u) {
        int i = base + u * 256 + tid;
        ok[u] = i < E;
        int ii = ok[u] ? i : E - 1;
        dv[u] = dst[ii];
        sv[u] = src[ii];
    }
    lh[tid] = 0;
    __syncthreads();
#pragma unroll
    for (int u = 0; u < 16; ++u)
        if (ok[u]) atomicAdd(&lh[dv[u] >> BSH], 1);
    __syncthreads();
    int c = lh[tid];
    lb[tid] = c ? atomicAdd(&bcursor[tid * PADS], c) : 0;
    lh[tid] = 0;
    __syncthreads();
#pragma unroll
    for (int u = 0; u < 16; ++u) {
        if (ok[u]) {
            int d = dv[u], b = d >> BSH;
            int pp = atomicAdd(&lh[b], 1);
            int pos = lb[b] + pp;
            if (pos < CAPQ)
                ebuf[b * CAPQ + pos] = (sv[u] << BSH) | (d & (BSZ - 1));
        }
    }
}

// ---------------- gemm0 body (512 thr, 128 rows/block) -----------------------
// K=128, OUTW=64, split-precision fp32 A (ah+al), bf16 W in LDS B-fragments.
// MFMA 16x16x32: A[m=lane&15][k=(lane>>4)*8+j], B[k][n=lane&15], C/D row=(lane>>4)*4+i.
__device__ __forceinline__ void gemm0_body(char* smem, int bid,
        const float* __restrict__ X, const float* __restrict__ W,
        const float* __restrict__ a_s, const float* __restrict__ a_d,
        unsigned int* __restrict__ hb, float* __restrict__ ss, float* __restrict__ sd, int N) {
    constexpr int K = 128, OUTW = 64, NKC = K / 32, NC = OUTW / 16;
    short* wfrag = (short*)smem;                                   // 16 KB
    unsigned int* hs = (unsigned int*)(smem + 16384);              // 16 KB: 8 waves x 512 uints

    const int tid  = threadIdx.x;
    const int lane = tid & 63;
    const int w    = tid >> 6;        // wave 0..7
    const int m    = lane & 15;
    const int q8   = lane >> 4;
    const int rowbase = bid * 128 + w * 16;

    for (int f = tid; f < NKC * NC * 64; f += 512) {
        int flane = f & 63;
        int fc    = (f >> 6) % NC;
        int fkc   = (f >> 6) / NC;
        int col   = fc * 16 + (flane & 15);
        int k0    = fkc * 32 + (flane >> 4) * 8;
        short8 b;
#pragma unroll
        for (int j = 0; j < 8; ++j) b[j] = (short)f2bf(W[(k0 + j) * OUTW + col]);
        *(short8*)&wfrag[f * 8] = b;
    }
    __syncthreads();

    int grow = rowbase + m; if (grow >= N) grow = N - 1;

    f32x4 acc[NC];
#pragma unroll
    for (int c = 0; c < NC; ++c) acc[c] = (f32x4)0.f;

    const float* xrow = X + (size_t)grow * K + q8 * 8;
#pragma unroll
    for (int kc = 0; kc < NKC; ++kc) {
        float4 v0 = *(const float4*)(xrow + kc * 32);
        float4 v1 = *(const float4*)(xrow + kc * 32 + 4);
        float vv[8] = {v0.x, v0.y, v0.z, v0.w, v1.x, v1.y, v1.z, v1.w};
        short8 ah, al;
#pragma unroll
        for (int j = 0; j < 8; ++j) {
            unsigned int hb16 = f2bf(vv[j]);
            ah[j] = (short)hb16;
            al[j] = (short)f2bf(vv[j] - __uint_as_float(hb16 << 16));
        }
#pragma unroll
        for (int c = 0; c < NC; ++c) {
            short8 b = *(short8*)&wfrag[((kc * NC + c) * 64 + lane) * 8];
            acc[c] = __builtin_amdgcn_mfma_f32_16x16x32_bf16(ah, b, acc[c], 0, 0, 0);
            acc[c] = __builtin_amdgcn_mfma_f32_16x16x32_bf16(al, b, acc[c], 0, 0, 0);
        }
    }

    // attention scores ss = h . a_s, sd = h . a_d
    float asv[NC], adv[NC];
#pragma unroll
    for (int c = 0; c < NC; ++c) { asv[c] = a_s[c * 16 + m]; adv[c] = a_d[c * 16 + m]; }
#pragma unroll
    for (int i = 0; i < 4; ++i) {
        float s = 0.f, d = 0.f;
#pragma unroll
        for (int c = 0; c < NC; ++c) {
            s = fmaf(acc[c][i], asv[c], s);
            d = fmaf(acc[c][i], adv[c], d);
        }
#pragma unroll
        for (int o = 1; o <= 8; o <<= 1) {
            s += __shfl_xor(s, o, 64);
            d += __shfl_xor(d, o, 64);
        }
        int r = rowbase + q8 * 4 + i;
        if (m == 0 && r < N) { ss[r] = s; sd[r] = d; }
    }

    // bf16-packed row write via per-wave LDS transpose (same wave, no barrier)
    unsigned short* hsw = (unsigned short*)&hs[w * 512];
#pragma unroll
    for (int c = 0; c < NC; ++c)
#pragma unroll
        for (int i = 0; i < 4; ++i)
            hsw[(q8 * 4 + i) * 64 + c * 16 + m] = (unsigned short)f2bf(acc[c][i]);
    unsigned int* hu = &hs[w * 512];
    int row = lane >> 2, u0 = (lane & 3) * 8;
    uint4 va = *(uint4*)&hu[row * 32 + u0];
    uint4 vb = *(uint4*)&hu[row * 32 + u0 + 4];
    int r = rowbase + row;
    if (r < N) {
        *(uint4*)&hb[(size_t)r * 32 + u0]     = va;
        *(uint4*)&hb[(size_t)r * 32 + u0 + 4] = vb;
    }
}

// ---------------- CSR build body (512 thr, inline cursor scan) ---------------
__device__ __forceinline__ void build_body(char* smem, int b,
        const int* __restrict__ bcursor, const int* __restrict__ ebuf,
        int* __restrict__ rowptr, int* __restrict__ csr,
        int N, int nbuck) {
    int* sdeg  = (int*)smem;          // 512
    int* sscan = sdeg + 512;          // 512
    int* shdr  = sscan + 512;         // 2
    const int t = threadIdx.x;

    int nlo = b << BSH;
    int cn = N - nlo; if (cn > BSZ) cn = BSZ;

    int bcv = 0, totv = 0;
    if (t < 256) {
        int cnb = 0;
        if (t < nbuck) {
            bcv = bcursor[t * PADS]; if (bcv > CAPQ) bcv = CAPQ;
            cnb = N - (t << BSH); if (cnb > BSZ) cnb = BSZ; if (cnb < 0) cnb = 0;
        }
        totv = bcv + cnb;
        sscan[t] = totv;
    }
    __syncthreads();
#pragma unroll
    for (int off = 1; off < 256; off <<= 1) {
        int u = 0;
        if (t < 256 && t >= off) u = sscan[t - off];
        __syncthreads();
        if (t < 256) sscan[t] += u;
        __syncthreads();
    }
    if (t == b) { shdr[0] = sscan[t] - totv; shdr[1] = bcv; }
    if (b == 0 && t == nbuck - 1) rowptr[N] = sscan[t];
    __syncthreads();
    int cb = shdr[0], ec = shdr[1];
    int e0 = b * CAPQ;

    sdeg[t] = (t < cn) ? 1 : 0;
    __syncthreads();
    {
        int i = t;
        for (; i + 1536 < ec; i += 2048) {
            int r0 = ebuf[e0 + i], r1 = ebuf[e0 + i + 512];
            int r2 = ebuf[e0 + i + 1024], r3 = ebuf[e0 + i + 1536];
            atomicAdd(&sdeg[r0 & (BSZ - 1)], 1);
            atomicAdd(&sdeg[r1 & (BSZ - 1)], 1);
            atomicAdd(&sdeg[r2 & (BSZ - 1)], 1);
            atomicAdd(&sdeg[r3 & (BSZ - 1)], 1);
        }
        for (; i < ec; i += 512)
            atomicAdd(&sdeg[ebuf[e0 + i] & (BSZ - 1)], 1);
    }
    __syncthreads();
    int v = sdeg[t];
    sscan[t] = v;
    __syncthreads();
#pragma unroll
    for (int off = 1; off < BSZ; off <<= 1) {
        int u = (t >= off) ? sscan[t - off] : 0;
        __syncthreads();
        sscan[t] += u;
        __syncthreads();
    }
    int excl = sscan[t] - v;
    if (t < cn) {
        rowptr[nlo + t] = cb + excl;
        csr[cb + excl] = nlo + t;
        sdeg[t] = excl + 1;
    }
    __syncthreads();
    {
        int i = t;
        for (; i + 1536 < ec; i += 2048) {
            int r0 = ebuf[e0 + i], r1 = ebuf[e0 + i + 512];
            int r2 = ebuf[e0 + i + 1024], r3 = ebuf[e0 + i + 1536];
            int p0 = atomicAdd(&sdeg[r0 & (BSZ - 1)], 1);
            int p1 = atomicAdd(&sdeg[r1 & (BSZ - 1)], 1);
            int p2 = atomicAdd(&sdeg[r2 & (BSZ - 1)], 1);
            int p3 = atomicAdd(&sdeg[r3 & (BSZ - 1)], 1);
            csr[cb + p0] = r0 >> BSH;
            csr[cb + p1] = r1 >> BSH;
            csr[cb + p2] = r2 >> BSH;
            csr[cb + p3] = r3 >> BSH;
        }
        for (; i < ec; i += 512) {
            int rec = ebuf[e0 + i];
            int p = atomicAdd(&sdeg[rec & (BSZ - 1)], 1);
            csr[cb + p] = rec >> BSH;
        }
    }
}

// ---------------- fused agg + next-layer GEMM (tile body + phase loop) -------
// Identical numerics to the verified round-9 k_aggmm; wfrag staged ONCE per
// block (amortized over all tiles the block processes).

template <int OUTW, bool LAST>
__device__ __forceinline__ void aggmm_phase(char* smemraw, int bid, int nblk, int gagg,
        const int* __restrict__ rowptr, const int* __restrict__ csr,
        const float* __restrict__ ss, const float* __restrict__ sd,
        const unsigned int* __restrict__ hb, const float* __restrict__ bias,
        const float* __restrict__ W, const float* __restrict__ a_s2,
        const float* __restrict__ a_d2,
        unsigned int* __restrict__ hbout, float* __restrict__ ssout,
        float* __restrict__ sdout,
        const float* __restrict__ bias2, float* __restrict__ fout, int N) {
    constexpr int NKC = 2;                 // K = 64
    constexpr int NC  = (OUTW + 15) / 16;
    constexpr int WB  = NKC * NC * 64 * 8 * 2;
    short* wfrag = (short*)smemraw;
    float (*sal)[CAP]   = (float(*)[CAP])(smemraw + WB);
    int   (*sof)[CAP]   = (int(*)[CAP])(smemraw + WB + 16 * CAP * 4);
    short (*afrag)[512] = (short(*)[512])(smemraw + WB + 2 * 16 * CAP * 4);
    unsigned short* hsw = (unsigned short*)(smemraw + WB + 2 * 16 * CAP * 4 + NKC * 512 * 2);
    float (*ssp)[16] = (float(*)[16])(smemraw + WB + 2 * 16 * CAP * 4 + NKC * 512 * 2 + 16 * 64 * 2);
    float (*sdp)[16] = (float(*)[16])((char*)ssp + NC * 16 * 4);

    const int tid  = threadIdx.x;
    const int lane = tid & 63;
    const int w    = tid >> 6;
    const int m    = lane & 15;
    const int q8   = lane >> 4;
    const int hw   = tid >> 5;
    const int p    = tid & 31;
    const int p4   = p * 4;
    const char* hbb = (const char*)hb;

    // stage W as B-fragments once per block
    for (int f = tid; f < NKC * NC * 64; f += 512) {
        int flane = f & 63;
        int fc    = (f >> 6) % NC;
        int fkc   = (f >> 6) / NC;
        int col   = fc * 16 + (flane & 15);
        int k0    = fkc * 32 + (flane >> 4) * 8;
        short8 b;
#pragma unroll
        for (int j = 0; j < 8; ++j) {
            float v = (col < OUTW) ? W[(k0 + j) * OUTW + col] : 0.f;
            b[j] = (short)f2bf(v);
        }
        *(short8*)&wfrag[f * 8] = b;
    }
    __syncthreads();

    for (int tile = bid; tile < gagg; tile += nblk) {
        const int nb = tile * 16;
        const int n  = nb + hw;
        const bool valid = n < N;

        int ro = 0, deg = 0;
        float sdn = 0.f;
        if (valid) {
            ro  = rowptr[n];
            deg = rowptr[n + 1] - ro;
            sdn = sd[n];
        }

        float fxr, fyr, inv;
        if (deg <= CAP) {
            float sum = 0.f;
            for (int j = p; j < deg; j += 32) {
                int s = csr[ro + j];
                float e = ss[s] + sdn;
                e = fmaxf(e, NEG_SLOPE * e);
                float pe = __expf(e);
                sal[hw][j] = pe;
                sof[hw][j] = s << 7;       // byte offset s*128
                sum += pe;
            }
            sum = hred_sum(sum);
            inv = 1.f / (sum + 1e-16f);

            float ax = 0.f, ay = 0.f, bx = 0.f, by = 0.f, cx = 0.f, cy = 0.f, dx = 0.f, dy = 0.f;
            int j = 0;
            for (; j + 7 < deg; j += 8) {
                float4 al0 = *(const float4*)&sal[hw][j];
                float4 al1 = *(const float4*)&sal[hw][j + 4];
                int4   of0 = *(const int4*)&sof[hw][j];
                int4   of1 = *(const int4*)&sof[hw][j + 4];
                unsigned int u0 = *(const unsigned int*)(hbb + (of0.x + p4));
                unsigned int u1 = *(const unsigned int*)(hbb + (of0.y + p4));
                unsigned int u2 = *(const unsigned int*)(hbb + (of0.z + p4));
                unsigned int u3 = *(const unsigned int*)(hbb + (of0.w + p4));
                unsigned int u4 = *(const unsigned int*)(hbb + (of1.x + p4));
                unsigned int u5 = *(const unsigned int*)(hbb + (of1.y + p4));
                unsigned int u6 = *(const unsigned int*)(hbb + (of1.z + p4));
                unsigned int u7 = *(const unsigned int*)(hbb + (of1.w + p4));
                ax = fmaf(bflo(u0), al0.x, ax); ay = fmaf(bfhi(u0), al0.x, ay);
                bx = fmaf(bflo(u1), al0.y, bx); by = fmaf(bfhi(u1), al0.y, by);
                cx = fmaf(bflo(u2), al0.z, cx); cy = fmaf(bfhi(u2), al0.z, cy);
                dx = fmaf(bflo(u3), al0.w, dx); dy = fmaf(bfhi(u3), al0.w, dy);
                ax = fmaf(bflo(u4), al1.x, ax); ay = fmaf(bfhi(u4), al1.x, ay);
                bx = fmaf(bflo(u5), al1.y, bx); by = fmaf(bfhi(u5), al1.y, by);
                cx = fmaf(bflo(u6), al1.z, cx); cy = fmaf(bfhi(u6), al1.z, cy);
                dx = fmaf(bflo(u7), al1.w, dx); dy = fmaf(bfhi(u7), al1.w, dy);
            }
            for (; j + 3 < deg; j += 4) {
                float4 al0 = *(const float4*)&sal[hw][j];
                int4   of0 = *(const int4*)&sof[hw][j];
                unsigned int u0 = *(const unsigned int*)(hbb + (of0.x + p4));
                unsigned int u1 = *(const unsigned int*)(hbb + (of0.y + p4));
                unsigned int u2 = *(const unsigned int*)(hbb + (of0.z + p4));
                unsigned int u3 = *(const unsigned int*)(hbb + (of0.w + p4));
                ax = fmaf(bflo(u0), al0.x, ax); ay = fmaf(bfhi(u0), al0.x, ay);
                bx = fmaf(bflo(u1), al0.y, bx); by = fmaf(bfhi(u1), al0.y, by);
                cx = fmaf(bflo(u2), al0.z, cx); cy = fmaf(bfhi(u2), al0.z, cy);
                dx = fmaf(bflo(u3), al0.w, dx); dy = fmaf(bfhi(u3), al0.w, dy);
            }
            for (; j < deg; ++j) {
                float a = sal[hw][j];
                unsigned int u0 = *(const unsigned int*)(hbb + (sof[hw][j] + p4));
                ax = fmaf(bflo(u0), a, ax); ay = fmaf(bfhi(u0), a, ay);
            }
            fxr = (ax + bx) + (cx + dx);
            fyr = (ay + by) + (cy + dy);
        } else {
            float sum = 0.f;
            for (int j = p; j < deg; j += 32) {
                int s = csr[ro + j];
                float e = ss[s] + sdn;
                e = fmaxf(e, NEG_SLOPE * e);
                sum += __expf(e);
            }
            sum = hred_sum(sum);
            inv = 1.f / (sum + 1e-16f);
            float fx = 0.f, fy = 0.f;
            for (int j = 0; j < deg; ++j) {
                int s = csr[ro + j];
                float e = ss[s] + sdn;
                e = fmaxf(e, NEG_SLOPE * e);
                float pe = __expf(e);
                unsigned int u = *(const unsigned int*)(hbb + ((s << 7) + p4));
                fx = fmaf(bflo(u), pe, fx); fy = fmaf(bfhi(u), pe, fy);
            }
            fxr = fx; fyr = fy;
        }
        // bias + elu, deposit z row into afrag (A-fragment layout)
        {
            float2 ob = *(const float2*)&bias[p * 2];
            float ox = fmaf(fxr, inv, ob.x);
            float oy = fmaf(fyr, inv, ob.y);
            ox = (ox > 0.f) ? ox : __expf(ox) - 1.f;
            oy = (oy > 0.f) ? oy : __expf(oy) - 1.f;
            unsigned int zu = (f2bf(oy) << 16) | f2bf(ox);
            int k   = 2 * p;
            int kc  = k >> 5;
            int idx = ((((k & 31) >> 3) * 16 + hw) << 3) + (k & 7);
            *(unsigned int*)&afrag[kc][idx] = zu;
        }
        __syncthreads();

        // phase 2: 16xOUTW MFMA tile (waves 0..NC-1), epilogues
        if (w < NC) {
            f32x4 acc = (f32x4)0.f;
#pragma unroll
            for (int kc = 0; kc < NKC; ++kc) {
                short8 a = *(short8*)&afrag[kc][lane * 8];
                short8 b = *(short8*)&wfrag[((kc * NC + w) * 64 + lane) * 8];
                acc = __builtin_amdgcn_mfma_f32_16x16x32_bf16(a, b, acc, 0, 0, 0);
            }
            if constexpr (LAST) {
#pragma unroll
                for (int i = 0; i < 4; ++i) {
                    int r = nb + q8 * 4 + i;
                    int col = w * 16 + m;
                    if (r < N && col < OUTW)
                        fout[(size_t)r * OUTW + col] = acc[i] + bias2[col];
                }
            } else {
                float asv = a_s2[w * 16 + m];
                float adv = a_d2[w * 16 + m];
#pragma unroll
                for (int i = 0; i < 4; ++i) {
                    float s = acc[i] * asv, d = acc[i] * adv;
#pragma unroll
                    for (int o = 1; o <= 8; o <<= 1) {
                        s += __shfl_xor(s, o, 64);
                        d += __shfl_xor(d, o, 64);
                    }
                    if (m == 0) { ssp[w][q8 * 4 + i] = s; sdp[w][q8 * 4 + i] = d; }
                    hsw[(q8 * 4 + i) * 64 + w * 16 + m] = (unsigned short)f2bf(acc[i]);
                }
            }
        }
        if constexpr (!LAST) {
            __syncthreads();
            if (tid < 16) {
                int r = nb + tid;
                if (r < N) {
                    float s = 0.f, d = 0.f;
#pragma unroll
                    for (int c = 0; c < NC; ++c) { s += ssp[c][tid]; d += sdp[c][tid]; }
                    ssout[r] = s; sdout[r] = d;
                }
            }
            if (tid < 128) {
                int row = tid >> 3, seg = tid & 7;
                int r = nb + row;
                if (r < N) {
                    uint4 v = *(uint4*)&((unsigned int*)hsw)[row * 32 + seg * 4];
                    *(uint4*)&hbout[(size_t)r * 32 + seg * 4] = v;
                }
            }
        }
        __syncthreads();   // protect sal/sof/afrag/hsw reuse next tile
    }
}

// ---------------- cooperative mega-kernel ------------------------------------

__global__ __launch_bounds__(512) void k_all(
        const int* __restrict__ src, const int* __restrict__ dst,
        int* __restrict__ bcursor, int* __restrict__ ebuf,
        int E, int nscat, int gbm, int nbuck,
        const float* __restrict__ x, const float* __restrict__ W0,
        const float* __restrict__ as0, const float* __restrict__ ad0,
        unsigned int* __restrict__ hb0, float* __restrict__ ss0, float* __restrict__ sd0,
        int* __restrict__ rowptr, int* __restrict__ csr,
        const float* __restrict__ b0, const float* __restrict__ W1,
        const float* __restrict__ as1, const float* __restrict__ ad1,
        unsigned int* __restrict__ hb1, float* __restrict__ ss1, float* __restrict__ sd1,
        const float* __restrict__ b1, const float* __restrict__ Wl,
        const float* __restrict__ bl, float* __restrict__ out, int gagg, int N) {
    __shared__ __align__(16) char smem[32768];
    cg::grid_group grid = cg::this_grid();
    const int bid = blockIdx.x, nblk = gridDim.x, tid = threadIdx.x;

    // P0: zero bucket cursors (replaces the memset dispatch)
    if (bid == 0)
        for (int i = tid; i < 256 * PADS; i += 512) bcursor[i] = 0;
    grid.sync();

    // P1: scatter edges into fixed-capacity buckets
    for (int c = bid; c < nscat; c += nblk)
        scatter512_body(smem, c, src, dst, bcursor, ebuf, E);
    grid.sync();

    // P2: gemm0 || CSR build (independent roles)
    for (int r = bid; r < gbm + nbuck; r += nblk) {
        if (r < gbm) gemm0_body(smem, r, x, W0, as0, ad0, hb0, ss0, sd0, N);
        else         build_body(smem, r - gbm, bcursor, ebuf, rowptr, csr, N, nbuck);
        __syncthreads();
    }
    grid.sync();

    // P3: agg layer 0 + gemm1 fused
    aggmm_phase<64, false>(smem, bid, nblk, gagg, rowptr, csr, ss0, sd0, hb0, b0,
                           W1, as1, ad1, hb1, ss1, sd1, nullptr, nullptr, N);
    grid.sync();

    // P4: agg layer 1 + classifier fused
    aggmm_phase<40, true>(smem, bid, nblk, gagg, rowptr, csr, ss1, sd1, hb1, b1,
                          Wl, nullptr, nullptr, nullptr, nullptr, nullptr, bl, out, N);
}

// ---------------- fallback kernels (verified round-9 path) -------------------

__global__ __launch_bounds__(512) void k_mid(
        int* __restrict__ bcursor, int* __restrict__ ebuf, int gbm, int nbuck,
        const float* __restrict__ X, const float* __restrict__ W,
        const float* __restrict__ a_s, const float* __restrict__ a_d,
        unsigned int* __restrict__ hb, float* __restrict__ ss, float* __restrict__ sd,
        int* __restrict__ rowptr, int* __restrict__ csr, int N) {
    __shared__ __align__(16) char smem[32768];
    int bid = blockIdx.x;
    if (bid < gbm)
        gemm0_body(smem, bid, X, W, a_s, a_d, hb, ss, sd, N);
    else
        build_body(smem, bid - gbm, bcursor, ebuf, rowptr, csr, N, nbuck);
}

template <int OUTW, bool LAST>
__global__ __launch_bounds__(512) void k_aggmm(
        const int* __restrict__ rowptr, const int* __restrict__ csr,
        const float* __restrict__ ss, const float* __restrict__ sd,
        const unsigned int* __restrict__ hb, const float* __restrict__ bias,
        const float* __restrict__ W, const float* __restrict__ a_s2,
        const float* __restrict__ a_d2,
        unsigned int* __restrict__ hbout, float* __restrict__ ssout,
        float* __restrict__ sdout,
        const float* __restrict__ bias2, float* __restrict__ fout, int N) {
    __shared__ __align__(16) char smem[32768];
    aggmm_phase<OUTW, LAST>(smem, blockIdx.x, gridDim.x, blockIdx.x + 1,  // single tile
                            rowptr, csr, ss, sd, hb, bias, W, a_s2, a_d2,
                            hbout, ssout, sdout, bias2, fout, N);
}

// ---------------- launch ----------------

extern "C" void kernel_launch(void* const* d_in, const int* in_sizes, int n_in,
                              void* d_out, int out_size, void* d_ws, size_t ws_size,
                              hipStream_t stream) {
    const float* x   = (const float*)d_in[0];
    const int*   ei  = (const int*)d_in[1];
    const float* W0  = (const float*)d_in[2];
    const float* as0 = (const float*)d_in[3];
    const float* ad0 = (const float*)d_in[4];
    const float* b0  = (const float*)d_in[5];
    const float* W1  = (const float*)d_in[6];
    const float* as1 = (const float*)d_in[7];
    const float* ad1 = (const float*)d_in[8];
    const float* b1  = (const float*)d_in[9];
    const float* Wl  = (const float*)d_in[10];
    const float* bl  = (const float*)d_in[11];
    float* out = (float*)d_out;

    int N = in_sizes[0] / 128;
    int E = in_sizes[1] / 2;
    const int* srcp = ei;
    const int* dstp = ei + E;
    int nbuck = (N + BSZ - 1) >> BSH;

    char* wp = (char*)d_ws;
    auto alloc = [&](size_t bytes) { void* p = (void*)wp; wp += (bytes + 255) & ~(size_t)255; return p; };
    unsigned int* hb0 = (unsigned int*)alloc((size_t)N * 32 * 4);
    unsigned int* hb1 = (unsigned int*)alloc((size_t)N * 32 * 4);
    float* ss0     = (float*)alloc((size_t)N * 4);
    float* sd0     = (float*)alloc((size_t)N * 4);
    float* ss1     = (float*)alloc((size_t)N * 4);
    float* sd1     = (float*)alloc((size_t)N * 4);
    int*   rowptr  = (int*)alloc((size_t)(N + 1) * 4);
    int*   csr     = (int*)alloc((size_t)(E + N) * 4);
    int*   ebuf    = (int*)alloc((size_t)nbuck * CAPQ * 4);
    int*   bcursor = (int*)alloc(256 * PADS * 4);

    int nscat = (E + CHUNK - 1) / CHUNK;
    int gbm   = (N + 127) / 128;
    int gagg  = (N + 15) / 16;

    // try the cooperative single-dispatch path
    int occ = 0;
    hipError_t qerr = hipOccupancyMaxActiveBlocksPerMultiprocessor(
        &occ, reinterpret_cast<const void*>(k_all), 512, 0);
    if (qerr == hipSuccess && occ > 0) {
        int grid = occ * 256;
        if (grid > 1024) grid = 1024;
        void* kargs[] = { (void*)&srcp, (void*)&dstp, (void*)&bcursor, (void*)&ebuf,
                          (void*)&E, (void*)&nscat, (void*)&gbm, (void*)&nbuck,
                          (void*)&x, (void*)&W0, (void*)&as0, (void*)&ad0,
                          (void*)&hb0, (void*)&ss0, (void*)&sd0,
                          (void*)&rowptr, (void*)&csr,
                          (void*)&b0, (void*)&W1, (void*)&as1, (void*)&ad1,
                          (void*)&hb1, (void*)&ss1, (void*)&sd1,
                          (void*)&b1, (void*)&Wl, (void*)&bl,
                          (void*)&out, (void*)&gagg, (void*)&N };
        hipError_t ce = hipLaunchCooperativeKernel(
            reinterpret_cast<const void*>(k_all), dim3(grid), dim3(512), kargs, 0, stream);
        if (ce == hipSuccess) return;
        (void)hipGetLastError();   // clear sticky error, fall through
    }

    // fallback: verified 5-dispatch path
    hipMemsetAsync(bcursor, 0, 256 * PADS * 4, stream);
    k_scatter<<<nscat, 256, 0, stream>>>(srcp, dstp, bcursor, ebuf, E);
    k_mid<<<gbm + nbuck, 512, 0, stream>>>(bcursor, ebuf, gbm, nbuck,
                                           x, W0, as0, ad0, hb0, ss0, sd0,
                                           rowptr, csr, N);
    k_aggmm<64, false><<<gagg, 512, 0, stream>>>(rowptr, csr, ss0, sd0, hb0, b0,
                                                 W1, as1, ad1,
                                                 hb1, ss1, sd1, nullptr, nullptr, N);
    k_aggmm<40, true><<<gagg, 512, 0, stream>>>(rowptr, csr, ss1, sd1, hb1, b1,
                                                Wl, nullptr, nullptr,
                                                nullptr, nullptr, nullptr, bl, out, N);
}

// Round 11
// 237.988 us; speedup vs baseline: 2.1113x; 2.1113x over previous
//
#include <hip/hip_runtime.h>
#include <math.h>

#define NEG_SLOPE 0.2f
#define CAP 128     // max degree on the agg fast path (Poisson(17): P(deg>128) ~ 0; slow path covers)
#define BSH 9       // node-bucket shift: 512 nodes/bucket
#define BSZ 512
#define CHUNK 4096  // edges per scatter block (16 per thread @ 256 threads)
#define PADS 16     // counter padding (ints) -> one counter per 64B line
#define CAPQ 16384  // fixed bucket capacity (mean ~8.2K, sigma ~90 -> never overflows)

typedef __attribute__((ext_vector_type(8))) short short8;   // 8 bf16 (4 VGPRs)
typedef __attribute__((ext_vector_type(4))) float f32x4;    // MFMA C/D

__device__ __forceinline__ float hred_sum(float v) {   // 32-wide (half-wave) reduce
#pragma unroll
    for (int o = 16; o >= 1; o >>= 1) v += __shfl_xor(v, o, 64);
    return v;
}
// fp32 -> bf16 (RNE), and bf16(lo/hi of uint) -> fp32
__device__ __forceinline__ unsigned int f2bf(float f) {
    unsigned int u = __float_as_uint(f);
    return (u + 0x7fffu + ((u >> 16) & 1u)) >> 16;
}
__device__ __forceinline__ float bflo(unsigned int u) { return __uint_as_float(u << 16); }
__device__ __forceinline__ float bfhi(unsigned int u) { return __uint_as_float(u & 0xffff0000u); }

// ---------------- W fragment packer (256 thr) --------------------------------
// Packs W[K][OUTW] fp32 into bf16 MFMA B-fragments: entry f = (kc*NC+c)*64+lane
// holds B[k0..k0+7][col] with col = c*16+(lane&15), k0 = kc*32+(lane>>4)*8.
// Same f2bf as the old per-block staging -> bit-identical downstream.
__device__ __forceinline__ void packw_body(const float* __restrict__ W, short* __restrict__ dst,
                                           int OUTW, int NKC, int NC) {
    int tot = NKC * NC * 64;
    for (int f = threadIdx.x; f < tot; f += 256) {
        int flane = f & 63;
        int fc    = (f >> 6) % NC;
        int fkc   = (f >> 6) / NC;
        int col   = fc * 16 + (flane & 15);
        int k0    = fkc * 32 + (flane >> 4) * 8;
        short8 b;
#pragma unroll
        for (int j = 0; j < 8; ++j) {
            float v = (col < OUTW) ? W[(k0 + j) * OUTW + col] : 0.f;
            b[j] = (short)f2bf(v);
        }
        *(short8*)&dst[f * 8] = b;
    }
}

// ---------------- scatter (+ W packers riding the launch) --------------------

__global__ __launch_bounds__(256) void k_scatter(
        const int* __restrict__ src, const int* __restrict__ dst,
        int* __restrict__ bcursor, int* __restrict__ ebuf, int E, int nscat,
        const float* __restrict__ W0, const float* __restrict__ W1,
        const float* __restrict__ Wl,
        short* __restrict__ wpk0, short* __restrict__ wpk1, short* __restrict__ wpkl) {
    __shared__ int lh[256], lb[256];
    const int tid = threadIdx.x;
    const int bid = blockIdx.x;
    if (bid >= nscat) {                      // packer roles (independent of edges)
        int role = bid - nscat;
        if (role == 0)      packw_body(W0, wpk0, 64, 4, 4);
        else if (role == 1) packw_body(W1, wpk1, 64, 2, 4);
        else                packw_body(Wl, wpkl, 40, 2, 3);
        return;
    }
    int base = bid * CHUNK;
    int sv[16], dv[16];
    bool ok[16];
#pragma unroll
    for (int u = 0; u < 16; ++u) {
        int i = base + u * 256 + tid;
        ok[u] = i < E;
        int ii = ok[u] ? i : E - 1;
        dv[u] = dst[ii];
        sv[u] = src[ii];
    }
    lh[tid] = 0;
    __syncthreads();
#pragma unroll
    for (int u = 0; u < 16; ++u)
        if (ok[u]) atomicAdd(&lh[dv[u] >> BSH], 1);
    __syncthreads();
    int c = lh[tid];
    lb[tid] = c ? atomicAdd(&bcursor[tid * PADS], c) : 0;   // relative cursor (memset 0)
    lh[tid] = 0;
    __syncthreads();
#pragma unroll
    for (int u = 0; u < 16; ++u) {
        if (ok[u]) {
            int d = dv[u], b = d >> BSH;
            int pp = atomicAdd(&lh[b], 1);
            int pos = lb[b] + pp;
            if (pos < CAPQ)                                  // overflow guard (never for this input)
                ebuf[b * CAPQ + pos] = (sv[u] << BSH) | (d & (BSZ - 1));
        }
    }
}

// ---------------- fused mid: gemm0 || build (independent work, one launch) ---

// K=128, OUTW=64, split-precision fp32 A (ah+al), pre-packed bf16 W fragments.
// MFMA 16x16x32: A[m=lane&15][k=(lane>>4)*8+j], B[k][n=lane&15], C/D row=(lane>>4)*4+i.
__device__ __forceinline__ void gemm0_body(char* smem, int bid,
        const float* __restrict__ X, const short* __restrict__ wpk,
        const float* __restrict__ a_s, const float* __restrict__ a_d,
        unsigned int* __restrict__ hb, float* __restrict__ ss, float* __restrict__ sd, int N) {
    constexpr int K = 128, OUTW = 64, NKC = K / 32, NC = OUTW / 16;
    short* wfrag = (short*)smem;                                   // 16 KB
    unsigned int* hs = (unsigned int*)(smem + 16384);              // 16 KB: 8 waves x 512 uints

    const int tid  = threadIdx.x;
    const int lane = tid & 63;
    const int w    = tid >> 6;        // wave 0..7
    const int m    = lane & 15;
    const int q8   = lane >> 4;
    const int rowbase = bid * 128 + w * 16;

    for (int f = tid; f < NKC * NC * 64; f += 512)        // plain copy (pre-packed)
        *(uint4*)&wfrag[f * 8] = ((const uint4*)wpk)[f];
    __syncthreads();

    int grow = rowbase + m; if (grow >= N) grow = N - 1;

    f32x4 acc[NC];
#pragma unroll
    for (int c = 0; c < NC; ++c) acc[c] = (f32x4)0.f;

    const float* xrow = X + (size_t)grow * K + q8 * 8;
#pragma unroll
    for (int kc = 0; kc < NKC; ++kc) {
        float4 v0 = *(const float4*)(xrow + kc * 32);
        float4 v1 = *(const float4*)(xrow + kc * 32 + 4);
        float vv[8] = {v0.x, v0.y, v0.z, v0.w, v1.x, v1.y, v1.z, v1.w};
        short8 ah, al;
#pragma unroll
        for (int j = 0; j < 8; ++j) {
            unsigned int hb16 = f2bf(vv[j]);
            ah[j] = (short)hb16;
            al[j] = (short)f2bf(vv[j] - __uint_as_float(hb16 << 16));
        }
#pragma unroll
        for (int c = 0; c < NC; ++c) {
            short8 b = *(short8*)&wfrag[((kc * NC + c) * 64 + lane) * 8];
            acc[c] = __builtin_amdgcn_mfma_f32_16x16x32_bf16(ah, b, acc[c], 0, 0, 0);
            acc[c] = __builtin_amdgcn_mfma_f32_16x16x32_bf16(al, b, acc[c], 0, 0, 0);
        }
    }

    // attention scores ss = h . a_s, sd = h . a_d
    float asv[NC], adv[NC];
#pragma unroll
    for (int c = 0; c < NC; ++c) { asv[c] = a_s[c * 16 + m]; adv[c] = a_d[c * 16 + m]; }
#pragma unroll
    for (int i = 0; i < 4; ++i) {
        float s = 0.f, d = 0.f;
#pragma unroll
        for (int c = 0; c < NC; ++c) {
            s = fmaf(acc[c][i], asv[c], s);
            d = fmaf(acc[c][i], adv[c], d);
        }
#pragma unroll
        for (int o = 1; o <= 8; o <<= 1) {
            s += __shfl_xor(s, o, 64);
            d += __shfl_xor(d, o, 64);
        }
        int r = rowbase + q8 * 4 + i;
        if (m == 0 && r < N) { ss[r] = s; sd[r] = d; }
    }

    // bf16-packed row write via per-wave LDS transpose (same wave, no barrier)
    unsigned short* hsw = (unsigned short*)&hs[w * 512];
#pragma unroll
    for (int c = 0; c < NC; ++c)
#pragma unroll
        for (int i = 0; i < 4; ++i)
            hsw[(q8 * 4 + i) * 64 + c * 16 + m] = (unsigned short)f2bf(acc[c][i]);
    unsigned int* hu = &hs[w * 512];
    int row = lane >> 2, u0 = (lane & 3) * 8;
    uint4 va = *(uint4*)&hu[row * 32 + u0];
    uint4 vb = *(uint4*)&hu[row * 32 + u0 + 4];
    int r = rowbase + row;
    if (r < N) {
        *(uint4*)&hb[(size_t)r * 32 + u0]     = va;
        *(uint4*)&hb[(size_t)r * 32 + u0 + 4] = vb;
    }
}

// CSR build for one bucket: inline cursor scan, two passes over the bucket.
__device__ __forceinline__ void build_body(char* smem, int b,
        const int* __restrict__ bcursor, const int* __restrict__ ebuf,
        int* __restrict__ rowptr, int* __restrict__ csr,
        int N, int nbuck) {
    int* sdeg  = (int*)smem;          // 512
    int* sscan = sdeg + 512;          // 512
    int* shdr  = sscan + 512;         // 2
    const int t = threadIdx.x;

    int nlo = b << BSH;
    int cn = N - nlo; if (cn > BSZ) cn = BSZ;

    int bcv = 0, totv = 0;
    if (t < 256) {
        int cnb = 0;
        if (t < nbuck) {
            bcv = bcursor[t * PADS]; if (bcv > CAPQ) bcv = CAPQ;
            cnb = N - (t << BSH); if (cnb > BSZ) cnb = BSZ; if (cnb < 0) cnb = 0;
        }
        totv = bcv + cnb;
        sscan[t] = totv;
    }
    __syncthreads();
#pragma unroll
    for (int off = 1; off < 256; off <<= 1) {
        int u = 0;
        if (t < 256 && t >= off) u = sscan[t - off];
        __syncthreads();
        if (t < 256) sscan[t] += u;
        __syncthreads();
    }
    if (t == b) { shdr[0] = sscan[t] - totv; shdr[1] = bcv; }
    if (b == 0 && t == nbuck - 1) rowptr[N] = sscan[t];
    __syncthreads();
    int cb = shdr[0], ec = shdr[1];
    int e0 = b * CAPQ;

    sdeg[t] = (t < cn) ? 1 : 0;
    __syncthreads();
    {
        int i = t;
        for (; i + 1536 < ec; i += 2048) {
            int r0 = ebuf[e0 + i], r1 = ebuf[e0 + i + 512];
            int r2 = ebuf[e0 + i + 1024], r3 = ebuf[e0 + i + 1536];
            atomicAdd(&sdeg[r0 & (BSZ - 1)], 1);
            atomicAdd(&sdeg[r1 & (BSZ - 1)], 1);
            atomicAdd(&sdeg[r2 & (BSZ - 1)], 1);
            atomicAdd(&sdeg[r3 & (BSZ - 1)], 1);
        }
        for (; i < ec; i += 512)
            atomicAdd(&sdeg[ebuf[e0 + i] & (BSZ - 1)], 1);
    }
    __syncthreads();
    int v = sdeg[t];
    sscan[t] = v;
    __syncthreads();
#pragma unroll
    for (int off = 1; off < BSZ; off <<= 1) {
        int u = (t >= off) ? sscan[t - off] : 0;
        __syncthreads();
        sscan[t] += u;
        __syncthreads();
    }
    int excl = sscan[t] - v;
    if (t < cn) {
        rowptr[nlo + t] = cb + excl;
        csr[cb + excl] = nlo + t;
        sdeg[t] = excl + 1;
    }
    __syncthreads();
    {
        int i = t;
        for (; i + 1536 < ec; i += 2048) {
            int r0 = ebuf[e0 + i], r1 = ebuf[e0 + i + 512];
            int r2 = ebuf[e0 + i + 1024], r3 = ebuf[e0 + i + 1536];
            int p0 = atomicAdd(&sdeg[r0 & (BSZ - 1)], 1);
            int p1 = atomicAdd(&sdeg[r1 & (BSZ - 1)], 1);
            int p2 = atomicAdd(&sdeg[r2 & (BSZ - 1)], 1);
            int p3 = atomicAdd(&sdeg[r3 & (BSZ - 1)], 1);
            csr[cb + p0] = r0 >> BSH;
            csr[cb + p1] = r1 >> BSH;
            csr[cb + p2] = r2 >> BSH;
            csr[cb + p3] = r3 >> BSH;
        }
        for (; i < ec; i += 512) {
            int rec = ebuf[e0 + i];
            int p = atomicAdd(&sdeg[rec & (BSZ - 1)], 1);
            csr[cb + p] = rec >> BSH;
        }
    }
}

__global__ __launch_bounds__(512) void k_mid(
        int* __restrict__ bcursor, int* __restrict__ ebuf, int gbm, int nbuck,
        const float* __restrict__ X, const short* __restrict__ wpk0,
        const float* __restrict__ a_s, const float* __restrict__ a_d,
        unsigned int* __restrict__ hb, float* __restrict__ ss, float* __restrict__ sd,
        int* __restrict__ rowptr, int* __restrict__ csr, int N) {
    __shared__ __align__(16) char smem[32768];   // max(gemm 32KB, build 4.1KB)
    int bid = blockIdx.x;
    if (bid < gbm)
        gemm0_body(smem, bid, X, wpk0, a_s, a_d, hb, ss, sd, N);
    else
        build_body(smem, bid - gbm, bcursor, ebuf, rowptr, csr, N, nbuck);
}

// ---------------- fused agg + next-layer GEMM --------------------------------
// Block = 512 threads = 16 nodes (verified round-9 structure). Changes vs r9:
// W fragments come PRE-PACKED from global -- no LDS wfrag, no f2bf staging, no
// staging barrier; waves 0..NC-1 hold their 2 loop-invariant B-frags in regs.
// All arithmetic bit-identical to round 9.

template <int OUTW, bool LAST>
__global__ __launch_bounds__(512) void k_aggmm(
        const int* __restrict__ rowptr, const int* __restrict__ csr,
        const float* __restrict__ ss, const float* __restrict__ sd,
        const unsigned int* __restrict__ hb, const float* __restrict__ bias,
        const short* __restrict__ wpk, const float* __restrict__ a_s2,
        const float* __restrict__ a_d2,
        unsigned int* __restrict__ hbout, float* __restrict__ ssout,
        float* __restrict__ sdout,
        const float* __restrict__ bias2, float* __restrict__ fout, int N) {
    constexpr int NKC = 2;                 // K = 64
    constexpr int NC  = (OUTW + 15) / 16;
    __shared__ __align__(16) float sal[16][CAP];
    __shared__ __align__(16) int   sof[16][CAP];
    __shared__ __align__(16) short afrag[NKC][512];
    __shared__ __align__(16) unsigned short hsw[LAST ? 1 : 16][64];
    __shared__ float ssp[LAST ? 1 : NC][16], sdp[LAST ? 1 : NC][16];

    const int tid  = threadIdx.x;
    const int lane = tid & 63;
    const int w    = tid >> 6;
    const int m    = lane & 15;
    const int q8   = lane >> 4;

    // loop-invariant B-fragments straight to registers (L2-hot, 16B/lane each)
    short8 bq0, bq1;
    if (w < NC) {
        bq0 = *(const short8*)&wpk[((0 * NC + w) * 64 + lane) * 8];
        bq1 = *(const short8*)&wpk[((1 * NC + w) * 64 + lane) * 8];
    }

    // ---- phase 1: aggregation (verified structure, 16 nodes/block) ----
    const int hw = tid >> 5;
    const int p  = tid & 31;
    const int nb = blockIdx.x * 16;
    const int n  = nb + hw;
    const bool valid = n < N;
    const char* hbb = (const char*)hb;
    const int p4 = p * 4;

    int ro = 0, deg = 0;
    float sdn = 0.f;
    if (valid) {
        ro  = rowptr[n];
        deg = rowptr[n + 1] - ro;
        sdn = sd[n];
    }

    float fxr, fyr, inv;
    if (deg <= CAP) {
        float sum = 0.f;
        for (int j = p; j < deg; j += 32) {
            int s = csr[ro + j];
            float e = ss[s] + sdn;
            e = fmaxf(e, NEG_SLOPE * e);
            float pe = __expf(e);
            sal[hw][j] = pe;
            sof[hw][j] = s << 7;       // byte offset s*128
            sum += pe;
        }
        sum = hred_sum(sum);
        inv = 1.f / (sum + 1e-16f);

        float ax = 0.f, ay = 0.f, bx = 0.f, by = 0.f, cx = 0.f, cy = 0.f, dx = 0.f, dy = 0.f;
        int j = 0;
        for (; j + 7 < deg; j += 8) {
            float4 al0 = *(const float4*)&sal[hw][j];
            float4 al1 = *(const float4*)&sal[hw][j + 4];
            int4   of0 = *(const int4*)&sof[hw][j];
            int4   of1 = *(const int4*)&sof[hw][j + 4];
            unsigned int u0 = *(const unsigned int*)(hbb + (of0.x + p4));
            unsigned int u1 = *(const unsigned int*)(hbb + (of0.y + p4));
            unsigned int u2 = *(const unsigned int*)(hbb + (of0.z + p4));
            unsigned int u3 = *(const unsigned int*)(hbb + (of0.w + p4));
            unsigned int u4 = *(const unsigned int*)(hbb + (of1.x + p4));
            unsigned int u5 = *(const unsigned int*)(hbb + (of1.y + p4));
            unsigned int u6 = *(const unsigned int*)(hbb + (of1.z + p4));
            unsigned int u7 = *(const unsigned int*)(hbb + (of1.w + p4));
            ax = fmaf(bflo(u0), al0.x, ax); ay = fmaf(bfhi(u0), al0.x, ay);
            bx = fmaf(bflo(u1), al0.y, bx); by = fmaf(bfhi(u1), al0.y, by);
            cx = fmaf(bflo(u2), al0.z, cx); cy = fmaf(bfhi(u2), al0.z, cy);
            dx = fmaf(bflo(u3), al0.w, dx); dy = fmaf(bfhi(u3), al0.w, dy);
            ax = fmaf(bflo(u4), al1.x, ax); ay = fmaf(bfhi(u4), al1.x, ay);
            bx = fmaf(bflo(u5), al1.y, bx); by = fmaf(bfhi(u5), al1.y, by);
            cx = fmaf(bflo(u6), al1.z, cx); cy = fmaf(bfhi(u6), al1.z, cy);
            dx = fmaf(bflo(u7), al1.w, dx); dy = fmaf(bfhi(u7), al1.w, dy);
        }
        for (; j + 3 < deg; j += 4) {
            float4 al0 = *(const float4*)&sal[hw][j];
            int4   of0 = *(const int4*)&sof[hw][j];
            unsigned int u0 = *(const unsigned int*)(hbb + (of0.x + p4));
            unsigned int u1 = *(const unsigned int*)(hbb + (of0.y + p4));
            unsigned int u2 = *(const unsigned int*)(hbb + (of0.z + p4));
            unsigned int u3 = *(const unsigned int*)(hbb + (of0.w + p4));
            ax = fmaf(bflo(u0), al0.x, ax); ay = fmaf(bfhi(u0), al0.x, ay);
            bx = fmaf(bflo(u1), al0.y, bx); by = fmaf(bfhi(u1), al0.y, by);
            cx = fmaf(bflo(u2), al0.z, cx); cy = fmaf(bfhi(u2), al0.z, cy);
            dx = fmaf(bflo(u3), al0.w, dx); dy = fmaf(bfhi(u3), al0.w, dy);
        }
        for (; j < deg; ++j) {
            float a = sal[hw][j];
            unsigned int u0 = *(const unsigned int*)(hbb + (sof[hw][j] + p4));
            ax = fmaf(bflo(u0), a, ax); ay = fmaf(bfhi(u0), a, ay);
        }
        fxr = (ax + bx) + (cx + dx);
        fyr = (ay + by) + (cy + dy);
    } else {
        float sum = 0.f;
        for (int j = p; j < deg; j += 32) {
            int s = csr[ro + j];
            float e = ss[s] + sdn;
            e = fmaxf(e, NEG_SLOPE * e);
            sum += __expf(e);
        }
        sum = hred_sum(sum);
        inv = 1.f / (sum + 1e-16f);
        float fx = 0.f, fy = 0.f;
        for (int j = 0; j < deg; ++j) {
            int s = csr[ro + j];
            float e = ss[s] + sdn;
            e = fmaxf(e, NEG_SLOPE * e);
            float pe = __expf(e);
            unsigned int u = *(const unsigned int*)(hbb + ((s << 7) + p4));
            fx = fmaf(bflo(u), pe, fx); fy = fmaf(bfhi(u), pe, fy);
        }
        fxr = fx; fyr = fy;
    }
    // bias + elu, then deposit z row into afrag (A-fragment layout)
    {
        float2 ob = *(const float2*)&bias[p * 2];
        float ox = fmaf(fxr, inv, ob.x);
        float oy = fmaf(fyr, inv, ob.y);
        ox = (ox > 0.f) ? ox : __expf(ox) - 1.f;
        oy = (oy > 0.f) ? oy : __expf(oy) - 1.f;
        unsigned int zu = (f2bf(oy) << 16) | f2bf(ox);
        int k   = 2 * p;                 // even, k and k+1 share a k-octet
        int kc  = k >> 5;
        int idx = ((((k & 31) >> 3) * 16 + hw) << 3) + (k & 7);
        *(unsigned int*)&afrag[kc][idx] = zu;
    }
    __syncthreads();

    // ---- phase 2: 16xOUTW MFMA tile (waves 0..NC-1), epilogues ----
    if (w < NC) {
        f32x4 acc = (f32x4)0.f;
        {
            short8 a0 = *(short8*)&afrag[0][lane * 8];
            acc = __builtin_amdgcn_mfma_f32_16x16x32_bf16(a0, bq0, acc, 0, 0, 0);
            short8 a1 = *(short8*)&afrag[1][lane * 8];
            acc = __builtin_amdgcn_mfma_f32_16x16x32_bf16(a1, bq1, acc, 0, 0, 0);
        }
        if constexpr (LAST) {
#pragma unroll
            for (int i = 0; i < 4; ++i) {
                int r = nb + q8 * 4 + i;
                int col = w * 16 + m;
                if (r < N && col < OUTW)
                    fout[(size_t)r * OUTW + col] = acc[i] + bias2[col];
            }
        } else {
            float asv = a_s2[w * 16 + m];
            float adv = a_d2[w * 16 + m];
#pragma unroll
            for (int i = 0; i < 4; ++i) {
                float s = acc[i] * asv, d = acc[i] * adv;
#pragma unroll
                for (int o = 1; o <= 8; o <<= 1) {
                    s += __shfl_xor(s, o, 64);
                    d += __shfl_xor(d, o, 64);
                }
                if (m == 0) { ssp[w][q8 * 4 + i] = s; sdp[w][q8 * 4 + i] = d; }
                hsw[q8 * 4 + i][w * 16 + m] = (unsigned short)f2bf(acc[i]);
            }
        }
    }
    if constexpr (!LAST) {
        __syncthreads();
        if (tid < 16) {                       // ss/sd out (fixed-order sum -> deterministic)
            int r = nb + tid;
            if (r < N) {
                float s = 0.f, d = 0.f;
#pragma unroll
                for (int c = 0; c < NC; ++c) { s += ssp[c][tid]; d += sdp[c][tid]; }
                ssout[r] = s; sdout[r] = d;
            }
        }
        if (tid < 128) {                      // hb rows out (16 rows x 128B)
            int row = tid >> 3, seg = tid & 7;
            int r = nb + row;
            if (r < N) {
                uint4 v = *(uint4*)&((unsigned int*)hsw)[row * 32 + seg * 4];
                *(uint4*)&hbout[(size_t)r * 32 + seg * 4] = v;
            }
        }
    }
}

// ---------------- launch ----------------

extern "C" void kernel_launch(void* const* d_in, const int* in_sizes, int n_in,
                              void* d_out, int out_size, void* d_ws, size_t ws_size,
                              hipStream_t stream) {
    const float* x   = (const float*)d_in[0];
    const int*   ei  = (const int*)d_in[1];
    const float* W0  = (const float*)d_in[2];
    const float* as0 = (const float*)d_in[3];
    const float* ad0 = (const float*)d_in[4];
    const float* b0  = (const float*)d_in[5];
    const float* W1  = (const float*)d_in[6];
    const float* as1 = (const float*)d_in[7];
    const float* ad1 = (const float*)d_in[8];
    const float* b1  = (const float*)d_in[9];
    const float* Wl  = (const float*)d_in[10];
    const float* bl  = (const float*)d_in[11];
    float* out = (float*)d_out;

    int N = in_sizes[0] / 128;
    int E = in_sizes[1] / 2;
    const int* srcp = ei;
    const int* dstp = ei + E;
    int nbuck = (N + BSZ - 1) >> BSH;

    char* wp = (char*)d_ws;
    auto alloc = [&](size_t bytes) { void* p = (void*)wp; wp += (bytes + 255) & ~(size_t)255; return p; };
    unsigned int* hb0 = (unsigned int*)alloc((size_t)N * 32 * 4);  // bf16-packed h (layer 0)
    unsigned int* hb1 = (unsigned int*)alloc((size_t)N * 32 * 4);  // bf16-packed h (layer 1)
    float* ss0     = (float*)alloc((size_t)N * 4);
    float* sd0     = (float*)alloc((size_t)N * 4);
    float* ss1     = (float*)alloc((size_t)N * 4);
    float* sd1     = (float*)alloc((size_t)N * 4);
    int*   rowptr  = (int*)alloc((size_t)(N + 1) * 4);
    int*   csr     = (int*)alloc((size_t)(E + N) * 4);
    int*   ebuf    = (int*)alloc((size_t)nbuck * CAPQ * 4);        // fixed-capacity buckets
    int*   bcursor = (int*)alloc(256 * PADS * 4);
    short* wpk0    = (short*)alloc(4 * 4 * 64 * 8 * 2);            // 16 KB W0 fragments
    short* wpk1    = (short*)alloc(2 * 4 * 64 * 8 * 2);            // 8 KB W1 fragments
    short* wpkl    = (short*)alloc(2 * 3 * 64 * 8 * 2);            // 6 KB Wl fragments

    int nscat = (E + CHUNK - 1) / CHUNK;
    int gbm   = (N + 127) / 128;        // mid gemm0: 128 rows/block
    int gagg  = (N + 15) / 16;          // fused agg+mm blocks

    // front: zero cursors -> scatter (+3 W-packer blocks) -> (gemm0 || build).
    hipMemsetAsync(bcursor, 0, 256 * PADS * 4, stream);
    k_scatter<<<nscat + 3, 256, 0, stream>>>(srcp, dstp, bcursor, ebuf, E, nscat,
                                             W0, W1, Wl, wpk0, wpk1, wpkl);
    k_mid<<<gbm + nbuck, 512, 0, stream>>>(bcursor, ebuf, gbm, nbuck,
                                           x, wpk0, as0, ad0, hb0, ss0, sd0,
                                           rowptr, csr, N);

    // back: (agg0 + gemm1) fused, then (agg1 + classifier) fused.
    k_aggmm<64, false><<<gagg, 512, 0, stream>>>(rowptr, csr, ss0, sd0, hb0, b0,
                                                 wpk1, as1, ad1,
                                                 hb1, ss1, sd1, nullptr, nullptr, N);
    k_aggmm<40, true><<<gagg, 512, 0, stream>>>(rowptr, csr, ss1, sd1, hb1, b1,
                                                wpkl, nullptr, nullptr,
                                                nullptr, nullptr, nullptr, bl, out, N);
}